// Round 1
// 212.755 us; speedup vs baseline: 1.0664x; 1.0664x over previous
//
#include <hip/hip_runtime.h>
#include <hip/hip_fp16.h>

#define N_NODES  100000
#define N_EDGES  1200000
#define N_GRAPHS 1024
#define F        64
#define BN_EPS   1e-5f
#define NBUCK    ((N_NODES + 255) / 256)       // 391 buckets of 256 node IDs
#define NBLK     512                            // scatter chunks
#define CHUNK    ((N_EDGES + NBLK - 1) / NBLK)  // 2344 edges per chunk
#define MT       128                            // GEMM nodes per block
#define GEMM_BLOCKS ((N_NODES + MT - 1) / MT)   // 782
#define CE       3584                           // per-bucket edge capacity
#define LDA      72                             // padded k-stride (halves): 144B
                                                // rows -> 4-bank rotation, <=2-way

typedef _Float16 f16x8 __attribute__((ext_vector_type(8)));
typedef float f32x4 __attribute__((ext_vector_type(4)));

// ---------------------------------------------------------------------------
// prep: fused [gemm_uz (MFMA fp16) | chist].
// GEMM: 128 nodes x 128 outs (Uh|Zh) x K=64 per block via mfma_f32_16x16x32_f16.
// Swapped operands -> D^T: lane holds (node = lane&15, f = (lane>>4)*4+reg),
// so each lane stores 4 consecutive feats of one node as one 8B store.
// ---------------------------------------------------------------------------
__global__ __launch_bounds__(256) void prep(
    const float* __restrict__ feats, const float* __restrict__ Wself,
    const float* __restrict__ Wneigh, __half* __restrict__ Uh,
    __half* __restrict__ Zh, const int* __restrict__ dst,
    int* __restrict__ Ct, int* __restrict__ hgbits) {
  __shared__ __align__(16) char smraw[2 * 128 * LDA * 2];   // 36.9 KB
  int t = threadIdx.x;

  if (blockIdx.x >= GEMM_BLOCKS) {
    int* lh = (int*)smraw;
    int b = blockIdx.x - GEMM_BLOCKS;
    int zidx = b * 256 + t;
    if (zidx < N_GRAPHS * F) hgbits[zidx] = 0;
    for (int i = t; i < NBUCK; i += 256) lh[i] = 0;
    __syncthreads();
    int e0 = b * CHUNK, e1 = e0 + CHUNK;
    if (e1 > N_EDGES) e1 = N_EDGES;
    for (int e = e0 + t; e < e1; e += 256) atomicAdd(&lh[dst[e] >> 8], 1);
    __syncthreads();
    for (int i = t; i < NBUCK; i += 256) Ct[(size_t)b * NBUCK + i] = lh[i];
    return;
  }

  __half* As = (__half*)smraw;          // [128 nodes][LDA]  (k-major, padded)
  __half* Bs = As + 128 * LDA;          // [128 cols ][LDA]  (W^T, k-major)
  int mbase = blockIdx.x * MT;

  // --- stage A: feats fp32 -> fp16, row-major k-contiguous, padded ---
#pragma unroll
  for (int s = 0; s < 8; s++) {
    int idx = s * 256 + t;              // 2048 float4 slots = 128 x 16
    int row = idx >> 4, c4 = idx & 15;
    int gm = mbase + row;
    float4 v = (gm < N_NODES) ? *(const float4*)(feats + (size_t)gm * F + c4 * 4)
                              : make_float4(0.f, 0.f, 0.f, 0.f);
    union { __half h[4]; uint2 u; } pk;
    pk.h[0] = __float2half_rn(v.x); pk.h[1] = __float2half_rn(v.y);
    pk.h[2] = __float2half_rn(v.z); pk.h[3] = __float2half_rn(v.w);
    *(uint2*)(As + row * LDA + c4 * 4) = pk.u;
  }

  // --- stage B: [Wself|Wneigh] transposed to [col][k], fp16, padded ---
#pragma unroll
  for (int s = 0; s < 2; s++) {
    int unit = s * 256 + t;             // 512 units: 16 kq x 32 c4
    int kq = unit >> 5, c4 = unit & 31;
    const float* Wp = (c4 < 16) ? (Wself + c4 * 4) : (Wneigh + (c4 - 16) * 4);
    float4 w0 = *(const float4*)(Wp + (kq * 4 + 0) * 64);
    float4 w1 = *(const float4*)(Wp + (kq * 4 + 1) * 64);
    float4 w2 = *(const float4*)(Wp + (kq * 4 + 2) * 64);
    float4 w3 = *(const float4*)(Wp + (kq * 4 + 3) * 64);
    float a[4][4] = {{w0.x, w0.y, w0.z, w0.w}, {w1.x, w1.y, w1.z, w1.w},
                     {w2.x, w2.y, w2.z, w2.w}, {w3.x, w3.y, w3.z, w3.w}};
#pragma unroll
    for (int c = 0; c < 4; c++) {
      union { __half h[4]; uint2 u; } pk;
      pk.h[0] = __float2half_rn(a[0][c]); pk.h[1] = __float2half_rn(a[1][c]);
      pk.h[2] = __float2half_rn(a[2][c]); pk.h[3] = __float2half_rn(a[3][c]);
      *(uint2*)(Bs + (c4 * 4 + c) * LDA + kq * 4) = pk.u;
    }
  }
  __syncthreads();

  // --- MFMA: wave = 32-node stripe x 128 outs; 2x8 tiles of 16x16 ---
  int wave = t >> 6, lane = t & 63;
  int lr = lane & 15, kg = lane >> 4;
  int r0 = wave * 32;

  f32x4 acc[2][8];
#pragma unroll
  for (int i = 0; i < 2; i++)
#pragma unroll
    for (int j = 0; j < 8; j++) acc[i][j] = (f32x4){0.f, 0.f, 0.f, 0.f};

#pragma unroll
  for (int h = 0; h < 2; h++) {         // two K=32 halves
    f16x8 a0 = *(const f16x8*)(As + (r0 + lr) * LDA + h * 32 + kg * 8);
    f16x8 a1 = *(const f16x8*)(As + (r0 + 16 + lr) * LDA + h * 32 + kg * 8);
#pragma unroll
    for (int j = 0; j < 8; j++) {
      f16x8 wv = *(const f16x8*)(Bs + (j * 16 + lr) * LDA + h * 32 + kg * 8);
      acc[0][j] = __builtin_amdgcn_mfma_f32_16x16x32_f16(wv, a0, acc[0][j], 0, 0, 0);
      acc[1][j] = __builtin_amdgcn_mfma_f32_16x16x32_f16(wv, a1, acc[1][j], 0, 0, 0);
    }
  }

  // --- epilogue: D^T layout -> lane packs 4 consecutive feats of one node ---
#pragma unroll
  for (int i = 0; i < 2; i++) {
    int node = mbase + r0 + i * 16 + lr;
    if (node < N_NODES) {
#pragma unroll
      for (int j = 0; j < 8; j++) {
        int f = j * 16 + kg * 4;
        union { __half h[4]; uint2 u; } pk;
        pk.h[0] = __float2half_rn(acc[i][j][0]);
        pk.h[1] = __float2half_rn(acc[i][j][1]);
        pk.h[2] = __float2half_rn(acc[i][j][2]);
        pk.h[3] = __float2half_rn(acc[i][j][3]);
        __half* outp = (f < 64) ? (Uh + (size_t)node * F + f)
                                : (Zh + (size_t)node * F + (f - 64));
        *(uint2*)outp = pk.u;
      }
    }
  }
}

// ---------------------------------------------------------------------------
// cscan: per-bucket scan over chunk counts (proven).
// ---------------------------------------------------------------------------
__global__ __launch_bounds__(NBLK) void cscan(int* __restrict__ Ct,
                                              int* __restrict__ bcnt) {
  __shared__ int s[NBLK];
  int i = blockIdx.x, t = threadIdx.x;
  int v = Ct[(size_t)t * NBUCK + i];
  s[t] = v;
  __syncthreads();
  for (int off = 1; off < NBLK; off <<= 1) {
    int u = (t >= off) ? s[t - off] : 0;
    __syncthreads();
    s[t] += u;
    __syncthreads();
  }
  Ct[(size_t)t * NBUCK + i] = s[t] - v;
  if (t == NBLK - 1) bcnt[i] = s[NBLK - 1];
}

// ---------------------------------------------------------------------------
// bscan: scan 391 bucket totals -> bstart (proven).
// ---------------------------------------------------------------------------
__global__ __launch_bounds__(512) void bscan(const int* __restrict__ bcnt,
                                             int* __restrict__ bstart) {
  __shared__ int s[512];
  int t = threadIdx.x;
  int v = (t < NBUCK) ? bcnt[t] : 0;
  s[t] = v;
  __syncthreads();
  for (int off = 1; off < 512; off <<= 1) {
    int u = (t >= off) ? s[t - off] : 0;
    __syncthreads();
    s[t] += u;
    __syncthreads();
  }
  if (t < NBUCK) bstart[t] = s[t] - v;
  if (t == 0) bstart[NBUCK] = N_EDGES;
}

// ---------------------------------------------------------------------------
// cscat: deterministic scatter of packed (local_dst<<24 | src) (proven).
// ---------------------------------------------------------------------------
__global__ __launch_bounds__(256) void cscat(const int* __restrict__ src,
                                             const int* __restrict__ dst,
                                             const int* __restrict__ Ct,
                                             const int* __restrict__ bstart,
                                             int* __restrict__ pairs) {
  __shared__ int cur[NBUCK];
  int b = blockIdx.x, t = threadIdx.x;
  for (int i = t; i < NBUCK; i += 256)
    cur[i] = bstart[i] + Ct[(size_t)b * NBUCK + i];
  __syncthreads();
  int e0 = b * CHUNK, e1 = e0 + CHUNK;
  if (e1 > N_EDGES) e1 = N_EDGES;
  for (int e = e0 + t; e < e1; e += 256) {
    int d = dst[e];
    int pos = atomicAdd(&cur[d >> 8], 1);
    pairs[pos] = (int)((((unsigned)d & 255u) << 24) | (unsigned)src[e]);
  }
}

// ---------------------------------------------------------------------------
// gather_place: fused [place | gather]. One 1024-thread block per bucket.
// ---------------------------------------------------------------------------
__global__ __launch_bounds__(1024) void gather_place(
    const __half* __restrict__ Uh, const __half* __restrict__ Zh,
    const int* __restrict__ pairs, const int* __restrict__ bstart,
    const float* __restrict__ bneigh, const int* __restrict__ gids,
    int* __restrict__ hgbits) {
  __shared__ int eidx_l[CE];     // 14.3 KB
  __shared__ int rsl[256];
  __shared__ int lh[256];
  __shared__ int cur[256];
  int b = blockIdx.x, t = threadIdx.x;
  int nb0 = b << 8;
  int r0 = bstart[b], r1 = bstart[b + 1];
  int E = r1 - r0; if (E > CE) E = CE;   // capacity guard (never hit: max~3250)

  // --- phase 1: local place ---
  if (t < 256) lh[t] = 0;
  __syncthreads();
  for (int e = t; e < E; e += 1024)
    atomicAdd(&lh[((unsigned)pairs[r0 + e]) >> 24], 1);
  __syncthreads();
  if (t < 256) cur[t] = lh[t];
  __syncthreads();
  for (int off = 1; off < 256; off <<= 1) {
    int u = (t < 256 && t >= off) ? cur[t - off] : 0;
    __syncthreads();
    if (t < 256) cur[t] += u;
    __syncthreads();
  }
  if (t < 256) { int ex = cur[t] - lh[t]; rsl[t] = ex; cur[t] = ex; }
  __syncthreads();
  for (int e = t; e < E; e += 1024) {
    unsigned p = (unsigned)pairs[r0 + e];
    int pos = atomicAdd(&cur[p >> 24], 1);
    eidx_l[pos] = (int)(p & 0xFFFFFFu);
  }
  __syncthreads();

  // --- phase 2: gather + SAGE update + ReLU + per-graph max ---
  int wave = t >> 6, lane = t & 63;
  int fl = lane & 15, sub = lane >> 4;
  float4 b4 = *(const float4*)(bneigh + 4 * fl);
  int nl = wave * 16;
  int nend = nl + 16;
  if (nb0 + nl >= N_NODES) return;
  if (nb0 + nend > N_NODES) nend = N_NODES - nb0;

  int curg = gids[nb0 + nl];
  float4 gmax = {0.f, 0.f, 0.f, 0.f};

  for (; nl < nend; nl++) {
    int node = nb0 + nl;
    int rr  = rsl[nl];
    int deg = lh[nl];
    uint2 ur = *(const uint2*)(Uh + (size_t)node * F + 4 * fl);
    float sx = 0.f, sy = 0.f, sz = 0.f, sw = 0.f;
    for (int jj = 0; jj < deg; jj += 16) {
      int j0 = jj + sub;
      int s0 = (j0      < deg) ? eidx_l[rr + j0]      : 0;  // LDS broadcast
      int s1 = (j0 + 4  < deg) ? eidx_l[rr + j0 + 4]  : 0;
      int s2 = (j0 + 8  < deg) ? eidx_l[rr + j0 + 8]  : 0;
      int s3 = (j0 + 12 < deg) ? eidx_l[rr + j0 + 12] : 0;
      uint2 z0 = *(const uint2*)(Zh + (size_t)s0 * F + 4 * fl);
      uint2 z1 = *(const uint2*)(Zh + (size_t)s1 * F + 4 * fl);
      uint2 z2 = *(const uint2*)(Zh + (size_t)s2 * F + 4 * fl);
      uint2 z3 = *(const uint2*)(Zh + (size_t)s3 * F + 4 * fl);
      if (j0 < deg) {
        float2 f0 = __half22float2(*(__half2*)&z0.x);
        float2 f1 = __half22float2(*(__half2*)&z0.y);
        sx += f0.x; sy += f0.y; sz += f1.x; sw += f1.y;
      }
      if (j0 + 4 < deg) {
        float2 f0 = __half22float2(*(__half2*)&z1.x);
        float2 f1 = __half22float2(*(__half2*)&z1.y);
        sx += f0.x; sy += f0.y; sz += f1.x; sw += f1.y;
      }
      if (j0 + 8 < deg) {
        float2 f0 = __half22float2(*(__half2*)&z2.x);
        float2 f1 = __half22float2(*(__half2*)&z2.y);
        sx += f0.x; sy += f0.y; sz += f1.x; sw += f1.y;
      }
      if (j0 + 12 < deg) {
        float2 f0 = __half22float2(*(__half2*)&z3.x);
        float2 f1 = __half22float2(*(__half2*)&z3.y);
        sx += f0.x; sy += f0.y; sz += f1.x; sw += f1.y;
      }
    }
    sx += __shfl_xor(sx, 16); sy += __shfl_xor(sy, 16);
    sz += __shfl_xor(sz, 16); sw += __shfl_xor(sw, 16);
    sx += __shfl_xor(sx, 32); sy += __shfl_xor(sy, 32);
    sz += __shfl_xor(sz, 32); sw += __shfl_xor(sw, 32);
    float inv = 1.0f / fmaxf((float)deg, 1.0f);

    int g = gids[node];
    if (g != curg) {
      if (sub == 0) {
        int* hp = hgbits + (size_t)curg * F + 4 * fl;
        atomicMax(hp + 0, __float_as_int(gmax.x));
        atomicMax(hp + 1, __float_as_int(gmax.y));
        atomicMax(hp + 2, __float_as_int(gmax.z));
        atomicMax(hp + 3, __float_as_int(gmax.w));
      }
      curg = g; gmax = make_float4(0.f, 0.f, 0.f, 0.f);
    }

    float2 uf0 = __half22float2(*(__half2*)&ur.x);
    float2 uf1 = __half22float2(*(__half2*)&ur.y);
    gmax.x = fmaxf(gmax.x, fmaxf(uf0.x + sx * inv + b4.x, 0.f));
    gmax.y = fmaxf(gmax.y, fmaxf(uf0.y + sy * inv + b4.y, 0.f));
    gmax.z = fmaxf(gmax.z, fmaxf(uf1.x + sz * inv + b4.z, 0.f));
    gmax.w = fmaxf(gmax.w, fmaxf(uf1.y + sw * inv + b4.w, 0.f));
  }
  if (sub == 0) {
    int* hp = hgbits + (size_t)curg * F + 4 * fl;
    atomicMax(hp + 0, __float_as_int(gmax.x));
    atomicMax(hp + 1, __float_as_int(gmax.y));
    atomicMax(hp + 2, __float_as_int(gmax.z));
    atomicMax(hp + 3, __float_as_int(gmax.w));
  }
}

// ---------------------------------------------------------------------------
// MLP head: weights staged in LDS once, 8 graphs per block.
// ---------------------------------------------------------------------------
#define GPB 8
__global__ __launch_bounds__(128) void mlp(
    const float* __restrict__ hg,
    const float* __restrict__ W1, const float* __restrict__ b1,
    const float* __restrict__ g1, const float* __restrict__ be1,
    const float* __restrict__ rm1, const float* __restrict__ rv1,
    const float* __restrict__ W2, const float* __restrict__ b2,
    const float* __restrict__ g2, const float* __restrict__ be2,
    const float* __restrict__ rm2, const float* __restrict__ rv2,
    const float* __restrict__ W3, const float* __restrict__ b3,
    float* __restrict__ out) {
  __shared__ float W1s[64 * 128];
  __shared__ float W2s[128 * 64];
  __shared__ float W3s[64];
  __shared__ float sc1[128], sh1[128], b1s[128];
  __shared__ float sc2[64],  sh2[64],  b2s[64];
  __shared__ float s0[64], s1[128], s2[64];
  int t = threadIdx.x;

  for (int i = t; i < 64 * 128; i += 128) W1s[i] = W1[i];
  for (int i = t; i < 128 * 64; i += 128) W2s[i] = W2[i];
  if (t < 64) W3s[t] = W3[t];
  {
    float iv = rsqrtf(rv1[t] + BN_EPS);
    float sc = g1[t] * iv;
    sc1[t] = sc; sh1[t] = be1[t] - rm1[t] * sc; b1s[t] = b1[t];
  }
  if (t < 64) {
    float iv = rsqrtf(rv2[t] + BN_EPS);
    float sc = g2[t] * iv;
    sc2[t] = sc; sh2[t] = be2[t] - rm2[t] * sc; b2s[t] = b2[t];
  }
  __syncthreads();

  for (int gg = 0; gg < GPB; gg++) {
    int g = blockIdx.x * GPB + gg;
    if (t < 64) s0[t] = hg[(size_t)g * F + t];
    __syncthreads();
    {
      float acc = b1s[t];
      for (int i = 0; i < 64; i++) acc += s0[i] * W1s[i * 128 + t];
      acc = fmaxf(acc, 0.0f);
      s1[t] = acc * sc1[t] + sh1[t];
    }
    __syncthreads();
    if (t < 64) {
      float acc = b2s[t];
      for (int i = 0; i < 128; i++) acc += s1[i] * W2s[i * 64 + t];
      acc = fmaxf(acc, 0.0f);
      s2[t] = acc * sc2[t] + sh2[t];
    }
    __syncthreads();
    if (t < 64) {
      float p = s2[t] * W3s[t];
      for (int off = 32; off > 0; off >>= 1) p += __shfl_down(p, off);
      if (t == 0) out[g] = p + b3[0];
    }
    __syncthreads();
  }
}

// ---------------------------------------------------------------------------
extern "C" void kernel_launch(void* const* d_in, const int* in_sizes, int n_in,
                              void* d_out, int out_size, void* d_ws, size_t ws_size,
                              hipStream_t stream) {
  const float* feats  = (const float*)d_in[0];
  const int*   src    = (const int*)d_in[1];
  const int*   dst    = (const int*)d_in[2];
  const int*   gids   = (const int*)d_in[3];
  const float* Wself  = (const float*)d_in[4];
  const float* Wneigh = (const float*)d_in[5];
  const float* bneigh = (const float*)d_in[6];
  const float* W1  = (const float*)d_in[7];
  const float* b1  = (const float*)d_in[8];
  const float* g1  = (const float*)d_in[9];
  const float* be1 = (const float*)d_in[10];
  const float* rm1 = (const float*)d_in[11];
  const float* rv1 = (const float*)d_in[12];
  const float* W2  = (const float*)d_in[13];
  const float* b2  = (const float*)d_in[14];
  const float* g2  = (const float*)d_in[15];
  const float* be2 = (const float*)d_in[16];
  const float* rm2 = (const float*)d_in[17];
  const float* rv2 = (const float*)d_in[18];
  const float* W3  = (const float*)d_in[19];
  const float* b3  = (const float*)d_in[20];

  // ws layout: Uh | Zh | bstart | bcnt | hgbits | Ct | pairs
  __half* Uh   = (__half*)d_ws;                      // N_NODES*64 halves
  __half* Zh   = Uh + (size_t)N_NODES * F;           // N_NODES*64 halves
  int* bstart  = (int*)(Zh + (size_t)N_NODES * F);   // NBUCK+1
  int* bcnt    = bstart + (NBUCK + 1);               // NBUCK
  int* hgbits  = bcnt + NBUCK;                       // N_GRAPHS*F (zeroed in prep)
  int* Ct      = hgbits + (size_t)N_GRAPHS * F;      // NBLK*NBUCK
  int* pairs   = Ct + (size_t)NBLK * NBUCK;          // N_EDGES

  prep<<<GEMM_BLOCKS + NBLK, 256, 0, stream>>>(feats, Wself, Wneigh, Uh, Zh,
                                               dst, Ct, hgbits);
  cscan<<<NBUCK, NBLK, 0, stream>>>(Ct, bcnt);
  bscan<<<1, 512, 0, stream>>>(bcnt, bstart);
  cscat<<<NBLK, 256, 0, stream>>>(src, dst, Ct, bstart, pairs);
  gather_place<<<NBUCK, 1024, 0, stream>>>(Uh, Zh, pairs, bstart, bneigh,
                                           gids, hgbits);
  mlp<<<N_GRAPHS / GPB, 128, 0, stream>>>((const float*)hgbits,
                                          W1, b1, g1, be1, rm1, rv1,
                                          W2, b2, g2, be2, rm2, rv2, W3, b3,
                                          (float*)d_out);
}

// Round 2
// 208.977 us; speedup vs baseline: 1.0857x; 1.0181x over previous
//
#include <hip/hip_runtime.h>
#include <hip/hip_fp16.h>

#define N_NODES  100000
#define N_EDGES  1200000
#define N_GRAPHS 1024
#define F        64
#define BN_EPS   1e-5f
#define NBUCK    ((N_NODES + 255) / 256)       // 391 buckets of 256 node IDs
#define NBLK     512                            // scatter chunks
#define CHUNK    ((N_EDGES + NBLK - 1) / NBLK)  // 2344 edges per chunk
#define MT       128                            // GEMM nodes per block
#define GEMM_BLOCKS ((N_NODES + MT - 1) / MT)   // 782
#define CE       3584                           // per-bucket edge capacity
#define LDA      72                             // padded k-stride (halves): 144B

typedef _Float16 f16x8 __attribute__((ext_vector_type(8)));
typedef float f32x4 __attribute__((ext_vector_type(4)));

// ---------------------------------------------------------------------------
// prep: fused [gemm_uz (MFMA fp16) | chist->bcnt atomics].
// GEMM: 128 nodes x 128 outs (Uh|Zh) x K=64 per block via mfma_f32_16x16x32_f16.
// hist blocks: LDS chunk histogram -> atomicAdd into global bcnt[391]
// (replaces the 800KB Ct matrix + cscan kernel).
// ---------------------------------------------------------------------------
__global__ __launch_bounds__(256) void prep(
    const float* __restrict__ feats, const float* __restrict__ Wself,
    const float* __restrict__ Wneigh, __half* __restrict__ Uh,
    __half* __restrict__ Zh, const int* __restrict__ dst,
    int* __restrict__ bcnt, int* __restrict__ hgbits) {
  __shared__ __align__(16) char smraw[2 * 128 * LDA * 2];   // 36.9 KB
  int t = threadIdx.x;

  if (blockIdx.x >= GEMM_BLOCKS) {
    int* lh = (int*)smraw;
    int b = blockIdx.x - GEMM_BLOCKS;
    int zidx = b * 256 + t;
    if (zidx < N_GRAPHS * F) hgbits[zidx] = 0;
    for (int i = t; i < NBUCK; i += 256) lh[i] = 0;
    __syncthreads();
    int e0 = b * CHUNK, e1 = e0 + CHUNK;
    if (e1 > N_EDGES) e1 = N_EDGES;
    for (int e = e0 + t; e < e1; e += 256) atomicAdd(&lh[dst[e] >> 8], 1);
    __syncthreads();
    for (int i = t; i < NBUCK; i += 256) {
      int c = lh[i];
      if (c) atomicAdd(&bcnt[i], c);
    }
    return;
  }

  __half* As = (__half*)smraw;          // [128 nodes][LDA]  (k-major, padded)
  __half* Bs = As + 128 * LDA;          // [128 cols ][LDA]  (W^T, k-major)
  int mbase = blockIdx.x * MT;

  // --- stage A: feats fp32 -> fp16, row-major k-contiguous, padded ---
#pragma unroll
  for (int s = 0; s < 8; s++) {
    int idx = s * 256 + t;              // 2048 float4 slots = 128 x 16
    int row = idx >> 4, c4 = idx & 15;
    int gm = mbase + row;
    float4 v = (gm < N_NODES) ? *(const float4*)(feats + (size_t)gm * F + c4 * 4)
                              : make_float4(0.f, 0.f, 0.f, 0.f);
    union { __half h[4]; uint2 u; } pk;
    pk.h[0] = __float2half_rn(v.x); pk.h[1] = __float2half_rn(v.y);
    pk.h[2] = __float2half_rn(v.z); pk.h[3] = __float2half_rn(v.w);
    *(uint2*)(As + row * LDA + c4 * 4) = pk.u;
  }

  // --- stage B: [Wself|Wneigh] transposed to [col][k], fp16, padded ---
#pragma unroll
  for (int s = 0; s < 2; s++) {
    int unit = s * 256 + t;             // 512 units: 16 kq x 32 c4
    int kq = unit >> 5, c4 = unit & 31;
    const float* Wp = (c4 < 16) ? (Wself + c4 * 4) : (Wneigh + (c4 - 16) * 4);
    float4 w0 = *(const float4*)(Wp + (kq * 4 + 0) * 64);
    float4 w1 = *(const float4*)(Wp + (kq * 4 + 1) * 64);
    float4 w2 = *(const float4*)(Wp + (kq * 4 + 2) * 64);
    float4 w3 = *(const float4*)(Wp + (kq * 4 + 3) * 64);
    float a[4][4] = {{w0.x, w0.y, w0.z, w0.w}, {w1.x, w1.y, w1.z, w1.w},
                     {w2.x, w2.y, w2.z, w2.w}, {w3.x, w3.y, w3.z, w3.w}};
#pragma unroll
    for (int c = 0; c < 4; c++) {
      union { __half h[4]; uint2 u; } pk;
      pk.h[0] = __float2half_rn(a[0][c]); pk.h[1] = __float2half_rn(a[1][c]);
      pk.h[2] = __float2half_rn(a[2][c]); pk.h[3] = __float2half_rn(a[3][c]);
      *(uint2*)(Bs + (c4 * 4 + c) * LDA + kq * 4) = pk.u;
    }
  }
  __syncthreads();

  // --- MFMA: wave = 32-node stripe x 128 outs; 2x8 tiles of 16x16 ---
  int wave = t >> 6, lane = t & 63;
  int lr = lane & 15, kg = lane >> 4;
  int r0 = wave * 32;

  f32x4 acc[2][8];
#pragma unroll
  for (int i = 0; i < 2; i++)
#pragma unroll
    for (int j = 0; j < 8; j++) acc[i][j] = (f32x4){0.f, 0.f, 0.f, 0.f};

#pragma unroll
  for (int h = 0; h < 2; h++) {         // two K=32 halves
    f16x8 a0 = *(const f16x8*)(As + (r0 + lr) * LDA + h * 32 + kg * 8);
    f16x8 a1 = *(const f16x8*)(As + (r0 + 16 + lr) * LDA + h * 32 + kg * 8);
#pragma unroll
    for (int j = 0; j < 8; j++) {
      f16x8 wv = *(const f16x8*)(Bs + (j * 16 + lr) * LDA + h * 32 + kg * 8);
      acc[0][j] = __builtin_amdgcn_mfma_f32_16x16x32_f16(wv, a0, acc[0][j], 0, 0, 0);
      acc[1][j] = __builtin_amdgcn_mfma_f32_16x16x32_f16(wv, a1, acc[1][j], 0, 0, 0);
    }
  }

  // --- epilogue: D^T layout -> lane packs 4 consecutive feats of one node ---
#pragma unroll
  for (int i = 0; i < 2; i++) {
    int node = mbase + r0 + i * 16 + lr;
    if (node < N_NODES) {
#pragma unroll
      for (int j = 0; j < 8; j++) {
        int f = j * 16 + kg * 4;
        union { __half h[4]; uint2 u; } pk;
        pk.h[0] = __float2half_rn(acc[i][j][0]);
        pk.h[1] = __float2half_rn(acc[i][j][1]);
        pk.h[2] = __float2half_rn(acc[i][j][2]);
        pk.h[3] = __float2half_rn(acc[i][j][3]);
        __half* outp = (f < 64) ? (Uh + (size_t)node * F + f)
                                : (Zh + (size_t)node * F + (f - 64));
        *(uint2*)outp = pk.u;
      }
    }
  }
}

// ---------------------------------------------------------------------------
// scat: replaces cscan+bscan+cscat. Each block: LDS histogram of its chunk
// (dst cached in LDS), local Hillis-Steele scan of bcnt -> bstart, atomic
// range reservation in gcur, LDS-cursor scatter of packed pairs.
// Block 0 publishes bstart for gather_place. Non-deterministic within-bucket
// order (fp-sum rounding only; tolerance absorbs).
// ---------------------------------------------------------------------------
__global__ __launch_bounds__(512) void scat(
    const int* __restrict__ src, const int* __restrict__ dst,
    const int* __restrict__ bcnt, int* __restrict__ gcur,
    int* __restrict__ pairs, int* __restrict__ bstart) {
  __shared__ int sc[512];
  __shared__ int lh[NBUCK];
  __shared__ int cur[NBUCK];
  __shared__ int dcache[CHUNK];
  int b = blockIdx.x, t = threadIdx.x;
  if (t < NBUCK) lh[t] = 0;
  __syncthreads();
  int e0 = b * CHUNK, e1 = e0 + CHUNK;
  if (e1 > N_EDGES) e1 = N_EDGES;
  for (int e = e0 + t; e < e1; e += 512) {
    int d = dst[e];
    dcache[e - e0] = d;
    atomicAdd(&lh[d >> 8], 1);
  }
  int v = (t < NBUCK) ? bcnt[t] : 0;
  sc[t] = v;
  __syncthreads();                       // hist atomics also complete here
  for (int off = 1; off < 512; off <<= 1) {
    int u = (t >= off) ? sc[t - off] : 0;
    __syncthreads();
    sc[t] += u;
    __syncthreads();
  }
  if (t < NBUCK) {
    int base = sc[t] - v;                // exclusive prefix = bucket start
    cur[t] = base + atomicAdd(&gcur[t], lh[t]);
    if (b == 0) bstart[t] = base;
  }
  if (b == 0 && t == 0) bstart[NBUCK] = N_EDGES;
  __syncthreads();
  for (int e = e0 + t; e < e1; e += 512) {
    int d = dcache[e - e0];
    int pos = atomicAdd(&cur[d >> 8], 1);
    pairs[pos] = (int)((((unsigned)d & 255u) << 24) | (unsigned)src[e]);
  }
}

// ---------------------------------------------------------------------------
// gather_place: fused [place | gather]. One 1024-thread block per bucket.
// ---------------------------------------------------------------------------
__global__ __launch_bounds__(1024) void gather_place(
    const __half* __restrict__ Uh, const __half* __restrict__ Zh,
    const int* __restrict__ pairs, const int* __restrict__ bstart,
    const float* __restrict__ bneigh, const int* __restrict__ gids,
    int* __restrict__ hgbits) {
  __shared__ int eidx_l[CE];     // 14.3 KB
  __shared__ int rsl[256];
  __shared__ int lh[256];
  __shared__ int cur[256];
  int b = blockIdx.x, t = threadIdx.x;
  int nb0 = b << 8;
  int r0 = bstart[b], r1 = bstart[b + 1];
  int E = r1 - r0; if (E > CE) E = CE;   // capacity guard (never hit: max~3250)

  // --- phase 1: local place ---
  if (t < 256) lh[t] = 0;
  __syncthreads();
  for (int e = t; e < E; e += 1024)
    atomicAdd(&lh[((unsigned)pairs[r0 + e]) >> 24], 1);
  __syncthreads();
  if (t < 256) cur[t] = lh[t];
  __syncthreads();
  for (int off = 1; off < 256; off <<= 1) {
    int u = (t < 256 && t >= off) ? cur[t - off] : 0;
    __syncthreads();
    if (t < 256) cur[t] += u;
    __syncthreads();
  }
  if (t < 256) { int ex = cur[t] - lh[t]; rsl[t] = ex; cur[t] = ex; }
  __syncthreads();
  for (int e = t; e < E; e += 1024) {
    unsigned p = (unsigned)pairs[r0 + e];
    int pos = atomicAdd(&cur[p >> 24], 1);
    eidx_l[pos] = (int)(p & 0xFFFFFFu);
  }
  __syncthreads();

  // --- phase 2: gather + SAGE update + ReLU + per-graph max ---
  int wave = t >> 6, lane = t & 63;
  int fl = lane & 15, sub = lane >> 4;
  float4 b4 = *(const float4*)(bneigh + 4 * fl);
  int nl = wave * 16;
  int nend = nl + 16;
  if (nb0 + nl >= N_NODES) return;
  if (nb0 + nend > N_NODES) nend = N_NODES - nb0;

  int curg = gids[nb0 + nl];
  float4 gmax = {0.f, 0.f, 0.f, 0.f};

  for (; nl < nend; nl++) {
    int node = nb0 + nl;
    int rr  = rsl[nl];
    int deg = lh[nl];
    uint2 ur = *(const uint2*)(Uh + (size_t)node * F + 4 * fl);
    float sx = 0.f, sy = 0.f, sz = 0.f, sw = 0.f;
    for (int jj = 0; jj < deg; jj += 16) {
      int j0 = jj + sub;
      int s0 = (j0      < deg) ? eidx_l[rr + j0]      : 0;  // LDS broadcast
      int s1 = (j0 + 4  < deg) ? eidx_l[rr + j0 + 4]  : 0;
      int s2 = (j0 + 8  < deg) ? eidx_l[rr + j0 + 8]  : 0;
      int s3 = (j0 + 12 < deg) ? eidx_l[rr + j0 + 12] : 0;
      uint2 z0 = *(const uint2*)(Zh + (size_t)s0 * F + 4 * fl);
      uint2 z1 = *(const uint2*)(Zh + (size_t)s1 * F + 4 * fl);
      uint2 z2 = *(const uint2*)(Zh + (size_t)s2 * F + 4 * fl);
      uint2 z3 = *(const uint2*)(Zh + (size_t)s3 * F + 4 * fl);
      if (j0 < deg) {
        float2 f0 = __half22float2(*(__half2*)&z0.x);
        float2 f1 = __half22float2(*(__half2*)&z0.y);
        sx += f0.x; sy += f0.y; sz += f1.x; sw += f1.y;
      }
      if (j0 + 4 < deg) {
        float2 f0 = __half22float2(*(__half2*)&z1.x);
        float2 f1 = __half22float2(*(__half2*)&z1.y);
        sx += f0.x; sy += f0.y; sz += f1.x; sw += f1.y;
      }
      if (j0 + 8 < deg) {
        float2 f0 = __half22float2(*(__half2*)&z2.x);
        float2 f1 = __half22float2(*(__half2*)&z2.y);
        sx += f0.x; sy += f0.y; sz += f1.x; sw += f1.y;
      }
      if (j0 + 12 < deg) {
        float2 f0 = __half22float2(*(__half2*)&z3.x);
        float2 f1 = __half22float2(*(__half2*)&z3.y);
        sx += f0.x; sy += f0.y; sz += f1.x; sw += f1.y;
      }
    }
    sx += __shfl_xor(sx, 16); sy += __shfl_xor(sy, 16);
    sz += __shfl_xor(sz, 16); sw += __shfl_xor(sw, 16);
    sx += __shfl_xor(sx, 32); sy += __shfl_xor(sy, 32);
    sz += __shfl_xor(sz, 32); sw += __shfl_xor(sw, 32);
    float inv = 1.0f / fmaxf((float)deg, 1.0f);

    int g = gids[node];
    if (g != curg) {
      if (sub == 0) {
        int* hp = hgbits + (size_t)curg * F + 4 * fl;
        atomicMax(hp + 0, __float_as_int(gmax.x));
        atomicMax(hp + 1, __float_as_int(gmax.y));
        atomicMax(hp + 2, __float_as_int(gmax.z));
        atomicMax(hp + 3, __float_as_int(gmax.w));
      }
      curg = g; gmax = make_float4(0.f, 0.f, 0.f, 0.f);
    }

    float2 uf0 = __half22float2(*(__half2*)&ur.x);
    float2 uf1 = __half22float2(*(__half2*)&ur.y);
    gmax.x = fmaxf(gmax.x, fmaxf(uf0.x + sx * inv + b4.x, 0.f));
    gmax.y = fmaxf(gmax.y, fmaxf(uf0.y + sy * inv + b4.y, 0.f));
    gmax.z = fmaxf(gmax.z, fmaxf(uf1.x + sz * inv + b4.z, 0.f));
    gmax.w = fmaxf(gmax.w, fmaxf(uf1.y + sw * inv + b4.w, 0.f));
  }
  if (sub == 0) {
    int* hp = hgbits + (size_t)curg * F + 4 * fl;
    atomicMax(hp + 0, __float_as_int(gmax.x));
    atomicMax(hp + 1, __float_as_int(gmax.y));
    atomicMax(hp + 2, __float_as_int(gmax.z));
    atomicMax(hp + 3, __float_as_int(gmax.w));
  }
}

// ---------------------------------------------------------------------------
// MLP head: weights staged in LDS once, 2 graphs per block (512 blocks:
// cuts the per-block serial gemv chain 4x vs GPB=8; weights are L2-resident
// so the extra staging is ~free).
// ---------------------------------------------------------------------------
#define GPB 2
__global__ __launch_bounds__(128) void mlp(
    const float* __restrict__ hg,
    const float* __restrict__ W1, const float* __restrict__ b1,
    const float* __restrict__ g1, const float* __restrict__ be1,
    const float* __restrict__ rm1, const float* __restrict__ rv1,
    const float* __restrict__ W2, const float* __restrict__ b2,
    const float* __restrict__ g2, const float* __restrict__ be2,
    const float* __restrict__ rm2, const float* __restrict__ rv2,
    const float* __restrict__ W3, const float* __restrict__ b3,
    float* __restrict__ out) {
  __shared__ float W1s[64 * 128];
  __shared__ float W2s[128 * 64];
  __shared__ float W3s[64];
  __shared__ float sc1[128], sh1[128], b1s[128];
  __shared__ float sc2[64],  sh2[64],  b2s[64];
  __shared__ float s0[64], s1[128], s2[64];
  int t = threadIdx.x;

  for (int i = t; i < 64 * 128; i += 128) W1s[i] = W1[i];
  for (int i = t; i < 128 * 64; i += 128) W2s[i] = W2[i];
  if (t < 64) W3s[t] = W3[t];
  {
    float iv = rsqrtf(rv1[t] + BN_EPS);
    float sc = g1[t] * iv;
    sc1[t] = sc; sh1[t] = be1[t] - rm1[t] * sc; b1s[t] = b1[t];
  }
  if (t < 64) {
    float iv = rsqrtf(rv2[t] + BN_EPS);
    float sc = g2[t] * iv;
    sc2[t] = sc; sh2[t] = be2[t] - rm2[t] * sc; b2s[t] = b2[t];
  }
  __syncthreads();

  for (int gg = 0; gg < GPB; gg++) {
    int g = blockIdx.x * GPB + gg;
    if (t < 64) s0[t] = hg[(size_t)g * F + t];
    __syncthreads();
    {
      float acc = b1s[t];
      for (int i = 0; i < 64; i++) acc += s0[i] * W1s[i * 128 + t];
      acc = fmaxf(acc, 0.0f);
      s1[t] = acc * sc1[t] + sh1[t];
    }
    __syncthreads();
    if (t < 64) {
      float acc = b2s[t];
      for (int i = 0; i < 128; i++) acc += s1[i] * W2s[i * 64 + t];
      acc = fmaxf(acc, 0.0f);
      s2[t] = acc * sc2[t] + sh2[t];
    }
    __syncthreads();
    if (t < 64) {
      float p = s2[t] * W3s[t];
      for (int off = 32; off > 0; off >>= 1) p += __shfl_down(p, off);
      if (t == 0) out[g] = p + b3[0];
    }
    __syncthreads();
  }
}

// ---------------------------------------------------------------------------
extern "C" void kernel_launch(void* const* d_in, const int* in_sizes, int n_in,
                              void* d_out, int out_size, void* d_ws, size_t ws_size,
                              hipStream_t stream) {
  const float* feats  = (const float*)d_in[0];
  const int*   src    = (const int*)d_in[1];
  const int*   dst    = (const int*)d_in[2];
  const int*   gids   = (const int*)d_in[3];
  const float* Wself  = (const float*)d_in[4];
  const float* Wneigh = (const float*)d_in[5];
  const float* bneigh = (const float*)d_in[6];
  const float* W1  = (const float*)d_in[7];
  const float* b1  = (const float*)d_in[8];
  const float* g1  = (const float*)d_in[9];
  const float* be1 = (const float*)d_in[10];
  const float* rm1 = (const float*)d_in[11];
  const float* rv1 = (const float*)d_in[12];
  const float* W2  = (const float*)d_in[13];
  const float* b2  = (const float*)d_in[14];
  const float* g2  = (const float*)d_in[15];
  const float* be2 = (const float*)d_in[16];
  const float* rm2 = (const float*)d_in[17];
  const float* rv2 = (const float*)d_in[18];
  const float* W3  = (const float*)d_in[19];
  const float* b3  = (const float*)d_in[20];

  // ws layout: Uh | Zh | bstart | bcnt | gcur | hgbits | pairs
  __half* Uh   = (__half*)d_ws;                      // N_NODES*64 halves
  __half* Zh   = Uh + (size_t)N_NODES * F;           // N_NODES*64 halves
  int* bstart  = (int*)(Zh + (size_t)N_NODES * F);   // NBUCK+1
  int* bcnt    = bstart + (NBUCK + 1);               // NBUCK
  int* gcur    = bcnt + NBUCK;                       // NBUCK (adjacent to bcnt)
  int* hgbits  = gcur + NBUCK;                       // N_GRAPHS*F (zeroed in prep)
  int* pairs   = hgbits + (size_t)N_GRAPHS * F;      // N_EDGES

  hipMemsetAsync(bcnt, 0, 2 * NBUCK * sizeof(int), stream);  // bcnt + gcur

  prep<<<GEMM_BLOCKS + NBLK, 256, 0, stream>>>(feats, Wself, Wneigh, Uh, Zh,
                                               dst, bcnt, hgbits);
  scat<<<NBLK, 512, 0, stream>>>(src, dst, bcnt, gcur, pairs, bstart);
  gather_place<<<NBUCK, 1024, 0, stream>>>(Uh, Zh, pairs, bstart, bneigh,
                                           gids, hgbits);
  mlp<<<N_GRAPHS / GPB, 128, 0, stream>>>((const float*)hgbits,
                                          W1, b1, g1, be1, rm1, rv1,
                                          W2, b2, g2, be2, rm2, rv2, W3, b3,
                                          (float*)d_out);
}

// Round 3
// 191.831 us; speedup vs baseline: 1.1827x; 1.0894x over previous
//
#include <hip/hip_runtime.h>
#include <hip/hip_fp16.h>

#define N_NODES  100000
#define N_EDGES  1200000
#define N_GRAPHS 1024
#define F        64
#define BN_EPS   1e-5f
#define NBUCK    ((N_NODES + 255) / 256)       // 391 buckets of 256 node IDs
#define NBLK     512                            // scatter chunks
#define CHUNK    ((N_EDGES + NBLK - 1) / NBLK)  // 2344 edges per chunk
#define MT       128                            // GEMM nodes per block
#define GEMM_BLOCKS ((N_NODES + MT - 1) / MT)   // 782
#define CE       3584                           // per-bucket slab capacity
                                                // (binomial mu=3072 sd=55; +9.2sd;
                                                //  measured max ~3250; clamped)
#define LDA      72                             // padded k-stride (halves): 144B

typedef _Float16 f16x8 __attribute__((ext_vector_type(8)));
typedef float f32x4 __attribute__((ext_vector_type(4)));

// ---------------------------------------------------------------------------
// prepscat: fused [scat | gemm_uz (MFMA fp16)] — fully independent halves.
// blocks [0,NBLK): scat — LDS hist of chunk, atomic range reservation in
//   gcur[391], scatter packed (local_dst<<24|src) into per-bucket slab
//   pairs[b*CE ...]. No scan, no bstart, no separate hist pass.
// blocks [NBLK,...): GEMM 128 nodes x 128 outs x K=64 via mfma_f32_16x16x32_f16.
//   Swapped operands -> D^T: lane holds (node=lane&15, f=(lane>>4)*4+reg),
//   each lane stores 4 consecutive feats of one node as one 8B store.
// ---------------------------------------------------------------------------
__global__ __launch_bounds__(256) void prepscat(
    const float* __restrict__ feats, const float* __restrict__ Wself,
    const float* __restrict__ Wneigh, __half* __restrict__ Uh,
    __half* __restrict__ Zh, const int* __restrict__ src,
    const int* __restrict__ dst, int* __restrict__ gcur,
    int* __restrict__ pairs) {
  __shared__ __align__(16) char smraw[2 * 128 * LDA * 2];   // 36.9 KB
  int t = threadIdx.x;

  if (blockIdx.x < NBLK) {
    // ---- scat path ----
    int* dcache = (int*)smraw;           // CHUNK ints (9.4 KB)
    int* lh   = dcache + CHUNK;          // NBUCK
    int* lcur = lh + NBUCK;              // NBUCK
    int b = blockIdx.x;
    for (int i = t; i < NBUCK; i += 256) lh[i] = 0;
    __syncthreads();
    int e0 = b * CHUNK, e1 = e0 + CHUNK;
    if (e1 > N_EDGES) e1 = N_EDGES;
    for (int e = e0 + t; e < e1; e += 256) {
      int d = dst[e];
      dcache[e - e0] = d;
      atomicAdd(&lh[d >> 8], 1);
    }
    __syncthreads();
    for (int i = t; i < NBUCK; i += 256) {
      int c = lh[i];
      lcur[i] = c ? atomicAdd(&gcur[i], c) : 0;   // reserve [base, base+c)
    }
    __syncthreads();
    for (int e = e0 + t; e < e1; e += 256) {
      int d = dcache[e - e0];
      int pos = atomicAdd(&lcur[d >> 8], 1);
      if (pos < CE)
        pairs[(size_t)(d >> 8) * CE + pos] =
            (int)((((unsigned)d & 255u) << 24) | (unsigned)src[e]);
    }
    return;
  }

  // ---- GEMM path ----
  __half* As = (__half*)smraw;          // [128 nodes][LDA]  (k-major, padded)
  __half* Bs = As + 128 * LDA;          // [128 cols ][LDA]  (W^T, k-major)
  int mbase = (blockIdx.x - NBLK) * MT;

  // --- stage A: feats fp32 -> fp16, row-major k-contiguous, padded ---
#pragma unroll
  for (int s = 0; s < 8; s++) {
    int idx = s * 256 + t;              // 2048 float4 slots = 128 x 16
    int row = idx >> 4, c4 = idx & 15;
    int gm = mbase + row;
    float4 v = (gm < N_NODES) ? *(const float4*)(feats + (size_t)gm * F + c4 * 4)
                              : make_float4(0.f, 0.f, 0.f, 0.f);
    union { __half h[4]; uint2 u; } pk;
    pk.h[0] = __float2half_rn(v.x); pk.h[1] = __float2half_rn(v.y);
    pk.h[2] = __float2half_rn(v.z); pk.h[3] = __float2half_rn(v.w);
    *(uint2*)(As + row * LDA + c4 * 4) = pk.u;
  }

  // --- stage B: [Wself|Wneigh] transposed to [col][k], fp16, padded ---
#pragma unroll
  for (int s = 0; s < 2; s++) {
    int unit = s * 256 + t;             // 512 units: 16 kq x 32 c4
    int kq = unit >> 5, c4 = unit & 31;
    const float* Wp = (c4 < 16) ? (Wself + c4 * 4) : (Wneigh + (c4 - 16) * 4);
    float4 w0 = *(const float4*)(Wp + (kq * 4 + 0) * 64);
    float4 w1 = *(const float4*)(Wp + (kq * 4 + 1) * 64);
    float4 w2 = *(const float4*)(Wp + (kq * 4 + 2) * 64);
    float4 w3 = *(const float4*)(Wp + (kq * 4 + 3) * 64);
    float a[4][4] = {{w0.x, w0.y, w0.z, w0.w}, {w1.x, w1.y, w1.z, w1.w},
                     {w2.x, w2.y, w2.z, w2.w}, {w3.x, w3.y, w3.z, w3.w}};
#pragma unroll
    for (int c = 0; c < 4; c++) {
      union { __half h[4]; uint2 u; } pk;
      pk.h[0] = __float2half_rn(a[0][c]); pk.h[1] = __float2half_rn(a[1][c]);
      pk.h[2] = __float2half_rn(a[2][c]); pk.h[3] = __float2half_rn(a[3][c]);
      *(uint2*)(Bs + (c4 * 4 + c) * LDA + kq * 4) = pk.u;
    }
  }
  __syncthreads();

  // --- MFMA: wave = 32-node stripe x 128 outs; 2x8 tiles of 16x16 ---
  int wave = t >> 6, lane = t & 63;
  int lr = lane & 15, kg = lane >> 4;
  int r0 = wave * 32;

  f32x4 acc[2][8];
#pragma unroll
  for (int i = 0; i < 2; i++)
#pragma unroll
    for (int j = 0; j < 8; j++) acc[i][j] = (f32x4){0.f, 0.f, 0.f, 0.f};

#pragma unroll
  for (int h = 0; h < 2; h++) {         // two K=32 halves
    f16x8 a0 = *(const f16x8*)(As + (r0 + lr) * LDA + h * 32 + kg * 8);
    f16x8 a1 = *(const f16x8*)(As + (r0 + 16 + lr) * LDA + h * 32 + kg * 8);
#pragma unroll
    for (int j = 0; j < 8; j++) {
      f16x8 wv = *(const f16x8*)(Bs + (j * 16 + lr) * LDA + h * 32 + kg * 8);
      acc[0][j] = __builtin_amdgcn_mfma_f32_16x16x32_f16(wv, a0, acc[0][j], 0, 0, 0);
      acc[1][j] = __builtin_amdgcn_mfma_f32_16x16x32_f16(wv, a1, acc[1][j], 0, 0, 0);
    }
  }

  // --- epilogue: D^T layout -> lane packs 4 consecutive feats of one node ---
#pragma unroll
  for (int i = 0; i < 2; i++) {
    int node = mbase + r0 + i * 16 + lr;
    if (node < N_NODES) {
#pragma unroll
      for (int j = 0; j < 8; j++) {
        int f = j * 16 + kg * 4;
        union { __half h[4]; uint2 u; } pk;
        pk.h[0] = __float2half_rn(acc[i][j][0]);
        pk.h[1] = __float2half_rn(acc[i][j][1]);
        pk.h[2] = __float2half_rn(acc[i][j][2]);
        pk.h[3] = __float2half_rn(acc[i][j][3]);
        __half* outp = (f < 64) ? (Uh + (size_t)node * F + f)
                                : (Zh + (size_t)node * F + (f - 64));
        *(uint2*)outp = pk.u;
      }
    }
  }
}

// ---------------------------------------------------------------------------
// gather_place: fused [place | gather]. One 1024-thread block per bucket.
// Reads its slab pairs[b*CE .. b*CE+E), E = gcur[b].
// ---------------------------------------------------------------------------
__global__ __launch_bounds__(1024) void gather_place(
    const __half* __restrict__ Uh, const __half* __restrict__ Zh,
    const int* __restrict__ pairs, const int* __restrict__ gcur,
    const float* __restrict__ bneigh, const int* __restrict__ gids,
    int* __restrict__ hgbits) {
  __shared__ int eidx_l[CE];     // 14.3 KB
  __shared__ int rsl[256];
  __shared__ int lh[256];
  __shared__ int cur[256];
  int b = blockIdx.x, t = threadIdx.x;
  int nb0 = b << 8;
  const int* pr = pairs + (size_t)b * CE;
  int E = gcur[b]; if (E > CE) E = CE;   // capacity clamp (never hit: max~3250)

  // --- phase 1: local place ---
  if (t < 256) lh[t] = 0;
  __syncthreads();
  for (int e = t; e < E; e += 1024)
    atomicAdd(&lh[((unsigned)pr[e]) >> 24], 1);
  __syncthreads();
  if (t < 256) cur[t] = lh[t];
  __syncthreads();
  for (int off = 1; off < 256; off <<= 1) {
    int u = (t < 256 && t >= off) ? cur[t - off] : 0;
    __syncthreads();
    if (t < 256) cur[t] += u;
    __syncthreads();
  }
  if (t < 256) { int ex = cur[t] - lh[t]; rsl[t] = ex; cur[t] = ex; }
  __syncthreads();
  for (int e = t; e < E; e += 1024) {
    unsigned p = (unsigned)pr[e];
    int pos = atomicAdd(&cur[p >> 24], 1);
    eidx_l[pos] = (int)(p & 0xFFFFFFu);
  }
  __syncthreads();

  // --- phase 2: gather + SAGE update + ReLU + per-graph max ---
  int wave = t >> 6, lane = t & 63;
  int fl = lane & 15, sub = lane >> 4;
  float4 b4 = *(const float4*)(bneigh + 4 * fl);
  int nl = wave * 16;
  int nend = nl + 16;
  if (nb0 + nl >= N_NODES) return;
  if (nb0 + nend > N_NODES) nend = N_NODES - nb0;

  int curg = gids[nb0 + nl];
  float4 gmax = {0.f, 0.f, 0.f, 0.f};

  for (; nl < nend; nl++) {
    int node = nb0 + nl;
    int rr  = rsl[nl];
    int deg = lh[nl];
    uint2 ur = *(const uint2*)(Uh + (size_t)node * F + 4 * fl);
    float sx = 0.f, sy = 0.f, sz = 0.f, sw = 0.f;
    for (int jj = 0; jj < deg; jj += 16) {
      int j0 = jj + sub;
      int s0 = (j0      < deg) ? eidx_l[rr + j0]      : 0;  // LDS broadcast
      int s1 = (j0 + 4  < deg) ? eidx_l[rr + j0 + 4]  : 0;
      int s2 = (j0 + 8  < deg) ? eidx_l[rr + j0 + 8]  : 0;
      int s3 = (j0 + 12 < deg) ? eidx_l[rr + j0 + 12] : 0;
      uint2 z0 = *(const uint2*)(Zh + (size_t)s0 * F + 4 * fl);
      uint2 z1 = *(const uint2*)(Zh + (size_t)s1 * F + 4 * fl);
      uint2 z2 = *(const uint2*)(Zh + (size_t)s2 * F + 4 * fl);
      uint2 z3 = *(const uint2*)(Zh + (size_t)s3 * F + 4 * fl);
      if (j0 < deg) {
        float2 f0 = __half22float2(*(__half2*)&z0.x);
        float2 f1 = __half22float2(*(__half2*)&z0.y);
        sx += f0.x; sy += f0.y; sz += f1.x; sw += f1.y;
      }
      if (j0 + 4 < deg) {
        float2 f0 = __half22float2(*(__half2*)&z1.x);
        float2 f1 = __half22float2(*(__half2*)&z1.y);
        sx += f0.x; sy += f0.y; sz += f1.x; sw += f1.y;
      }
      if (j0 + 8 < deg) {
        float2 f0 = __half22float2(*(__half2*)&z2.x);
        float2 f1 = __half22float2(*(__half2*)&z2.y);
        sx += f0.x; sy += f0.y; sz += f1.x; sw += f1.y;
      }
      if (j0 + 12 < deg) {
        float2 f0 = __half22float2(*(__half2*)&z3.x);
        float2 f1 = __half22float2(*(__half2*)&z3.y);
        sx += f0.x; sy += f0.y; sz += f1.x; sw += f1.y;
      }
    }
    sx += __shfl_xor(sx, 16); sy += __shfl_xor(sy, 16);
    sz += __shfl_xor(sz, 16); sw += __shfl_xor(sw, 16);
    sx += __shfl_xor(sx, 32); sy += __shfl_xor(sy, 32);
    sz += __shfl_xor(sz, 32); sw += __shfl_xor(sw, 32);
    float inv = 1.0f / fmaxf((float)deg, 1.0f);

    int g = gids[node];
    if (g != curg) {
      if (sub == 0) {
        int* hp = hgbits + (size_t)curg * F + 4 * fl;
        atomicMax(hp + 0, __float_as_int(gmax.x));
        atomicMax(hp + 1, __float_as_int(gmax.y));
        atomicMax(hp + 2, __float_as_int(gmax.z));
        atomicMax(hp + 3, __float_as_int(gmax.w));
      }
      curg = g; gmax = make_float4(0.f, 0.f, 0.f, 0.f);
    }

    float2 uf0 = __half22float2(*(__half2*)&ur.x);
    float2 uf1 = __half22float2(*(__half2*)&ur.y);
    gmax.x = fmaxf(gmax.x, fmaxf(uf0.x + sx * inv + b4.x, 0.f));
    gmax.y = fmaxf(gmax.y, fmaxf(uf0.y + sy * inv + b4.y, 0.f));
    gmax.z = fmaxf(gmax.z, fmaxf(uf1.x + sz * inv + b4.z, 0.f));
    gmax.w = fmaxf(gmax.w, fmaxf(uf1.y + sw * inv + b4.w, 0.f));
  }
  if (sub == 0) {
    int* hp = hgbits + (size_t)curg * F + 4 * fl;
    atomicMax(hp + 0, __float_as_int(gmax.x));
    atomicMax(hp + 1, __float_as_int(gmax.y));
    atomicMax(hp + 2, __float_as_int(gmax.z));
    atomicMax(hp + 3, __float_as_int(gmax.w));
  }
}

// ---------------------------------------------------------------------------
// MLP head: weights staged in LDS once, 2 graphs per block.
// ---------------------------------------------------------------------------
#define GPB 2
__global__ __launch_bounds__(128) void mlp(
    const float* __restrict__ hg,
    const float* __restrict__ W1, const float* __restrict__ b1,
    const float* __restrict__ g1, const float* __restrict__ be1,
    const float* __restrict__ rm1, const float* __restrict__ rv1,
    const float* __restrict__ W2, const float* __restrict__ b2,
    const float* __restrict__ g2, const float* __restrict__ be2,
    const float* __restrict__ rm2, const float* __restrict__ rv2,
    const float* __restrict__ W3, const float* __restrict__ b3,
    float* __restrict__ out) {
  __shared__ float W1s[64 * 128];
  __shared__ float W2s[128 * 64];
  __shared__ float W3s[64];
  __shared__ float sc1[128], sh1[128], b1s[128];
  __shared__ float sc2[64],  sh2[64],  b2s[64];
  __shared__ float s0[64], s1[128], s2[64];
  int t = threadIdx.x;

  for (int i = t; i < 64 * 128; i += 128) W1s[i] = W1[i];
  for (int i = t; i < 128 * 64; i += 128) W2s[i] = W2[i];
  if (t < 64) W3s[t] = W3[t];
  {
    float iv = rsqrtf(rv1[t] + BN_EPS);
    float sc = g1[t] * iv;
    sc1[t] = sc; sh1[t] = be1[t] - rm1[t] * sc; b1s[t] = b1[t];
  }
  if (t < 64) {
    float iv = rsqrtf(rv2[t] + BN_EPS);
    float sc = g2[t] * iv;
    sc2[t] = sc; sh2[t] = be2[t] - rm2[t] * sc; b2s[t] = b2[t];
  }
  __syncthreads();

  for (int gg = 0; gg < GPB; gg++) {
    int g = blockIdx.x * GPB + gg;
    if (t < 64) s0[t] = hg[(size_t)g * F + t];
    __syncthreads();
    {
      float acc = b1s[t];
      for (int i = 0; i < 64; i++) acc += s0[i] * W1s[i * 128 + t];
      acc = fmaxf(acc, 0.0f);
      s1[t] = acc * sc1[t] + sh1[t];
    }
    __syncthreads();
    if (t < 64) {
      float acc = b2s[t];
      for (int i = 0; i < 128; i++) acc += s1[i] * W2s[i * 64 + t];
      acc = fmaxf(acc, 0.0f);
      s2[t] = acc * sc2[t] + sh2[t];
    }
    __syncthreads();
    if (t < 64) {
      float p = s2[t] * W3s[t];
      for (int off = 32; off > 0; off >>= 1) p += __shfl_down(p, off);
      if (t == 0) out[g] = p + b3[0];
    }
    __syncthreads();
  }
}

// ---------------------------------------------------------------------------
extern "C" void kernel_launch(void* const* d_in, const int* in_sizes, int n_in,
                              void* d_out, int out_size, void* d_ws, size_t ws_size,
                              hipStream_t stream) {
  const float* feats  = (const float*)d_in[0];
  const int*   src    = (const int*)d_in[1];
  const int*   dst    = (const int*)d_in[2];
  const int*   gids   = (const int*)d_in[3];
  const float* Wself  = (const float*)d_in[4];
  const float* Wneigh = (const float*)d_in[5];
  const float* bneigh = (const float*)d_in[6];
  const float* W1  = (const float*)d_in[7];
  const float* b1  = (const float*)d_in[8];
  const float* g1  = (const float*)d_in[9];
  const float* be1 = (const float*)d_in[10];
  const float* rm1 = (const float*)d_in[11];
  const float* rv1 = (const float*)d_in[12];
  const float* W2  = (const float*)d_in[13];
  const float* b2  = (const float*)d_in[14];
  const float* g2  = (const float*)d_in[15];
  const float* be2 = (const float*)d_in[16];
  const float* rm2 = (const float*)d_in[17];
  const float* rv2 = (const float*)d_in[18];
  const float* W3  = (const float*)d_in[19];
  const float* b3  = (const float*)d_in[20];

  // ws layout: Uh | Zh | gcur | hgbits | pairs   (gcur+hgbits = one memset)
  __half* Uh   = (__half*)d_ws;                      // N_NODES*64 halves
  __half* Zh   = Uh + (size_t)N_NODES * F;           // N_NODES*64 halves
  int* gcur    = (int*)(Zh + (size_t)N_NODES * F);   // NBUCK
  int* hgbits  = gcur + NBUCK;                       // N_GRAPHS*F
  int* pairs   = hgbits + (size_t)N_GRAPHS * F;      // NBUCK*CE slabs

  hipMemsetAsync(gcur, 0, (NBUCK + N_GRAPHS * F) * sizeof(int), stream);

  prepscat<<<NBLK + GEMM_BLOCKS, 256, 0, stream>>>(feats, Wself, Wneigh,
                                                   Uh, Zh, src, dst, gcur, pairs);
  gather_place<<<NBUCK, 1024, 0, stream>>>(Uh, Zh, pairs, gcur, bneigh,
                                           gids, hgbits);
  mlp<<<N_GRAPHS / GPB, 128, 0, stream>>>((const float*)hgbits,
                                          W1, b1, g1, be1, rm1, rv1,
                                          W2, b2, g2, be2, rm2, rv2, W3, b3,
                                          (float*)d_out);
}